// Round 1
// baseline (399.402 us; speedup 1.0000x reference)
//
#include <hip/hip_runtime.h>
#include <hip/hip_bf16.h>
#include <math.h>

// Problem constants (match reference)
#define BETA     0.05f
#define BG_KNN   50
#define N_CAMS   6
#define CLS      2000
#define DIM      2048
#define BATCH    256
#define NPROXY   (N_CAMS * CLS)     // 12000
#define MASK_VAL -10000.0f

// ---------------- GEMM: sims[B][NPROXY] = feats @ mem^T (both row-major, K contiguous) ---
#define BM 64
#define BN 128
#define BK 16

__global__ __launch_bounds__(256) void gemm_bt(const float* __restrict__ A,   // [BATCH][DIM]
                                               const float* __restrict__ Bm,  // [NPROXY][DIM]
                                               float* __restrict__ C)         // [BATCH][NPROXY]
{
    __shared__ float As[BK][BM + 4];
    __shared__ float Bs[BK][BN + 4];
    const int bm = blockIdx.y * BM;
    const int bn = blockIdx.x * BN;
    const int tid = threadIdx.x;
    const int tr = tid >> 4;    // 0..15
    const int tc = tid & 15;    // 0..15

    float acc[4][8];
#pragma unroll
    for (int i = 0; i < 4; ++i)
#pragma unroll
        for (int j = 0; j < 8; ++j) acc[i][j] = 0.f;

    for (int k0 = 0; k0 < DIM; k0 += BK) {
        // Load A tile: BM x BK = 1024 floats -> 4 per thread (one float4)
        {
            int e = tid * 4;
            int r = e >> 4;         // /BK
            int c = e & 15;
            float4 v = *(const float4*)(A + (size_t)(bm + r) * DIM + k0 + c);
            As[c + 0][r] = v.x; As[c + 1][r] = v.y; As[c + 2][r] = v.z; As[c + 3][r] = v.w;
        }
        // Load B tile: BN x BK = 2048 floats -> 8 per thread (two float4)
        {
            int e = tid * 8;
            int r = e >> 4;
            int c = e & 15;         // 0 or 8
            int gr = bn + r;
            float4 v0, v1;
            if (gr < NPROXY) {
                const float4* p = (const float4*)(Bm + (size_t)gr * DIM + k0 + c);
                v0 = p[0]; v1 = p[1];
            } else {
                v0 = make_float4(0.f, 0.f, 0.f, 0.f);
                v1 = v0;
            }
            Bs[c + 0][r] = v0.x; Bs[c + 1][r] = v0.y; Bs[c + 2][r] = v0.z; Bs[c + 3][r] = v0.w;
            Bs[c + 4][r] = v1.x; Bs[c + 5][r] = v1.y; Bs[c + 6][r] = v1.z; Bs[c + 7][r] = v1.w;
        }
        __syncthreads();
#pragma unroll
        for (int k = 0; k < BK; ++k) {
            float a[4], b[8];
#pragma unroll
            for (int i = 0; i < 4; ++i) a[i] = As[k][tr * 4 + i];
#pragma unroll
            for (int j = 0; j < 8; ++j) b[j] = Bs[k][tc * 8 + j];
#pragma unroll
            for (int i = 0; i < 4; ++i)
#pragma unroll
                for (int j = 0; j < 8; ++j) acc[i][j] += a[i] * b[j];
        }
        __syncthreads();
    }
#pragma unroll
    for (int i = 0; i < 4; ++i) {
        int row = bm + tr * 4 + i;
#pragma unroll
        for (int j = 0; j < 8; ++j) {
            int col = bn + tc * 8 + j;
            if (col < NPROXY) C[(size_t)row * NPROXY + col] = acc[i][j];
        }
    }
}

// ---------------- Per-sample: CE + top-50 hard negatives + assoc term ----------------
__global__ __launch_bounds__(256) void per_sample(const float* __restrict__ sims,
                                                  const int* __restrict__ cams,
                                                  const int* __restrict__ labels,
                                                  float* __restrict__ ce_out,
                                                  float* __restrict__ assoc_out)
{
    __shared__ float row[NPROXY];       // 48000 B
    __shared__ float red[256];
    __shared__ int   redi[256];
    __shared__ float pos_sh[N_CAMS];
    __shared__ float negv[BG_KNN];

    const int i   = blockIdx.x;
    const int tid = threadIdx.x;
    const float* s = sims + (size_t)i * NPROXY;
    const int cc  = cams[i];
    const int lab = labels[i];

    // stage row in LDS
    for (int p = tid; p < NPROXY; p += 256) row[p] = s[p];
    __syncthreads();

    // ---- CE over own-camera block (unmasked values) ----
    const int base = cc * CLS;
    float lmax = -1e30f;
    for (int c = tid; c < CLS; c += 256) lmax = fmaxf(lmax, row[base + c]);
    red[tid] = lmax; __syncthreads();
    for (int st = 128; st > 0; st >>= 1) {
        if (tid < st) red[tid] = fmaxf(red[tid], red[tid + st]);
        __syncthreads();
    }
    float smax = red[0];
    __syncthreads();
    float lsum = 0.f;
    for (int c = tid; c < CLS; c += 256) lsum += expf((row[base + c] - smax) / BETA);
    red[tid] = lsum; __syncthreads();
    for (int st = 128; st > 0; st >>= 1) {
        if (tid < st) red[tid] += red[tid + st];
        __syncthreads();
    }
    if (tid == 0) ce_out[i] = logf(red[0]) + (smax - row[base + lab]) / BETA;
    __syncthreads();

    // ---- record positives and mask them ----
    if (tid < N_CAMS) {
        float v = row[tid * CLS + lab];
        pos_sh[tid] = v;
        row[tid * CLS + lab] = MASK_VAL;
    }
    __syncthreads();

    // ---- top-50 by iterative block argmax ----
    for (int it = 0; it < BG_KNN; ++it) {
        float bv = -1e30f; int bi = 0;
        for (int p = tid; p < NPROXY; p += 256) {
            float v = row[p];
            if (v > bv) { bv = v; bi = p; }
        }
        red[tid] = bv; redi[tid] = bi; __syncthreads();
        for (int st = 128; st > 0; st >>= 1) {
            if (tid < st) {
                float ov = red[tid + st]; int oi = redi[tid + st];
                if (ov > red[tid] || (ov == red[tid] && oi < redi[tid])) {
                    red[tid] = ov; redi[tid] = oi;
                }
            }
            __syncthreads();
        }
        if (tid == 0) {
            negv[it] = red[0];
            row[redi[0]] = -1e30f;   // remove from further selection
        }
        __syncthreads();
    }

    // ---- assoc loss over 6 pos + 50 neg logits ----
    if (tid == 0) {
        float m = -1e30f;
        for (int j = 0; j < N_CAMS; ++j) m = fmaxf(m, pos_sh[j]);
        for (int j = 0; j < BG_KNN; ++j) m = fmaxf(m, negv[j]);
        float ssum = 0.f;
        for (int j = 0; j < N_CAMS; ++j) ssum += expf((pos_sh[j] - m) / BETA);
        for (int j = 0; j < BG_KNN; ++j) ssum += expf((negv[j] - m) / BETA);
        float lse = m / BETA + logf(ssum);
        float psum = 0.f;
        for (int j = 0; j < N_CAMS; ++j) psum += pos_sh[j];
        assoc_out[i] = lse - psum / (N_CAMS * BETA);
    }
}

// ---------------- Finalize: per-camera segment means -> scalar loss ----------------
__global__ __launch_bounds__(64) void finalize(const int* __restrict__ cams,
                                               const float* __restrict__ ce,
                                               const float* __restrict__ assoc,
                                               float* __restrict__ out)
{
    __shared__ float ce_s[N_CAMS], as_s[N_CAMS];
    __shared__ int   cnt[N_CAMS];
    int tid = threadIdx.x;
    if (tid < N_CAMS) {
        float cs = 0.f, as = 0.f; int n = 0;
        for (int i = 0; i < BATCH; ++i) {
            if (cams[i] == tid) { cs += ce[i]; as += assoc[i]; ++n; }
        }
        ce_s[tid] = cs; as_s[tid] = as; cnt[tid] = n;
    }
    __syncthreads();
    if (tid == 0) {
        float loss = 0.f;
        for (int c = 0; c < N_CAMS; ++c) {
            if (cnt[c] > 0) {
                float inv = 1.f / (float)cnt[c];
                loss += ce_s[c] * inv + 0.5f * as_s[c] * inv;
            }
        }
        out[0] = loss;
    }
}

extern "C" void kernel_launch(void* const* d_in, const int* in_sizes, int n_in,
                              void* d_out, int out_size, void* d_ws, size_t ws_size,
                              hipStream_t stream) {
    const float* feats  = (const float*)d_in[0];   // [256][2048]
    const float* mem    = (const float*)d_in[1];   // [6][2000][2048] -> flat [12000][2048]
    const int*   cams   = (const int*)d_in[2];     // [256]
    const int*   labels = (const int*)d_in[3];     // [256]
    float* out = (float*)d_out;

    float* sims  = (float*)d_ws;                         // 256*12000 floats = 49.15 MB
    float* ce    = sims + (size_t)BATCH * NPROXY;        // 256 floats
    float* assoc = ce + BATCH;                           // 256 floats

    dim3 g_gemm((NPROXY + BN - 1) / BN, BATCH / BM);     // (94, 4)
    gemm_bt<<<g_gemm, 256, 0, stream>>>(feats, mem, sims);

    per_sample<<<BATCH, 256, 0, stream>>>(sims, cams, labels, ce, assoc);

    finalize<<<1, 64, 0, stream>>>(cams, ce, assoc, out);
}

// Round 2
// 151.168 us; speedup vs baseline: 2.6421x; 2.6421x over previous
//
#include <hip/hip_runtime.h>
#include <hip/hip_bf16.h>
#include <math.h>

#define BETA_INV 20.0f          // 1/0.05
#define BG_KNN   50
#define N_CAMS   6
#define CLS      2000
#define DIM      2048
#define BATCH    256
#define NPROXY   (N_CAMS * CLS)     // 12000
#define MASK_VAL -10000.0f

typedef __attribute__((ext_vector_type(8))) short short8;
typedef __attribute__((ext_vector_type(4))) float f32x4;

__device__ __forceinline__ unsigned short f2bf(float f) {
    unsigned u = __builtin_bit_cast(unsigned, f);
    unsigned r = 0x7FFFu + ((u >> 16) & 1u);
    return (unsigned short)((u + r) >> 16);
}

// ---------------- bf16 MFMA GEMM: sims[256][12000] = feats @ mem^T ----------------
// BM=64, BN=96, BK=32; 4 waves (2x2), wave tile 32x48 (2x3 16x16 frags)
#define GBM 64
#define GBN 96
#define GBK 32
#define LDP 40      // padded LDS row length (bf16 elems) -> 80B stride, conflict-free frag reads

__global__ __launch_bounds__(256) void gemm_mfma(const float* __restrict__ A,   // [256][2048]
                                                 const float* __restrict__ Bm,  // [12000][2048]
                                                 float* __restrict__ C)         // [256][12000]
{
    __shared__ unsigned short As[2][GBM][LDP];   // 10.0 KB
    __shared__ unsigned short Bs[2][GBN][LDP];   // 15.0 KB

    const int tid  = threadIdx.x;
    const int bid  = blockIdx.x;
    const int bm   = (bid & 3) * GBM;        // m varies fastest -> adjacent blocks share B panel
    const int bn   = (bid >> 2) * GBN;
    const int lane = tid & 63;
    const int wid  = tid >> 6;
    const int wm   = (wid >> 1) * 32;
    const int wn   = (wid & 1) * 48;
    const int fr   = lane & 15;
    const int kg   = lane >> 4;              // 0..3

    f32x4 acc[2][3];
#pragma unroll
    for (int i = 0; i < 2; ++i)
#pragma unroll
        for (int j = 0; j < 3; ++j) acc[i][j] = (f32x4){0.f, 0.f, 0.f, 0.f};

    float4 ar[2], br[3];

    // prologue: stage tile 0
#pragma unroll
    for (int q = 0; q < 2; ++q) {
        int li = q * 256 + tid, r = li >> 3, c = (li & 7) * 4;
        ar[q] = *(const float4*)(A + (size_t)(bm + r) * DIM + c);
    }
#pragma unroll
    for (int q = 0; q < 3; ++q) {
        int li = q * 256 + tid, r = li >> 3, c = (li & 7) * 4;
        br[q] = *(const float4*)(Bm + (size_t)(bn + r) * DIM + c);
    }
#pragma unroll
    for (int q = 0; q < 2; ++q) {
        int li = q * 256 + tid, r = li >> 3, c = (li & 7) * 4;
        ushort4 pk = {f2bf(ar[q].x), f2bf(ar[q].y), f2bf(ar[q].z), f2bf(ar[q].w)};
        *(ushort4*)&As[0][r][c] = pk;
    }
#pragma unroll
    for (int q = 0; q < 3; ++q) {
        int li = q * 256 + tid, r = li >> 3, c = (li & 7) * 4;
        ushort4 pk = {f2bf(br[q].x), f2bf(br[q].y), f2bf(br[q].z), f2bf(br[q].w)};
        *(ushort4*)&Bs[0][r][c] = pk;
    }
    __syncthreads();

    const int NT = DIM / GBK;   // 64
    for (int t = 0; t < NT; ++t) {
        const int buf = t & 1;
        if (t < NT - 1) {
            const int k0 = (t + 1) * GBK;
#pragma unroll
            for (int q = 0; q < 2; ++q) {
                int li = q * 256 + tid, r = li >> 3, c = (li & 7) * 4;
                ar[q] = *(const float4*)(A + (size_t)(bm + r) * DIM + k0 + c);
            }
#pragma unroll
            for (int q = 0; q < 3; ++q) {
                int li = q * 256 + tid, r = li >> 3, c = (li & 7) * 4;
                br[q] = *(const float4*)(Bm + (size_t)(bn + r) * DIM + k0 + c);
            }
        }
        short8 af[2], bf[3];
#pragma unroll
        for (int i = 0; i < 2; ++i)
            af[i] = *(const short8*)&As[buf][wm + i * 16 + fr][kg * 8];
#pragma unroll
        for (int j = 0; j < 3; ++j)
            bf[j] = *(const short8*)&Bs[buf][wn + j * 16 + fr][kg * 8];
#pragma unroll
        for (int i = 0; i < 2; ++i)
#pragma unroll
            for (int j = 0; j < 3; ++j)
                acc[i][j] = __builtin_amdgcn_mfma_f32_16x16x32_bf16(af[i], bf[j], acc[i][j], 0, 0, 0);
        if (t < NT - 1) {
            const int nb = buf ^ 1;
#pragma unroll
            for (int q = 0; q < 2; ++q) {
                int li = q * 256 + tid, r = li >> 3, c = (li & 7) * 4;
                ushort4 pk = {f2bf(ar[q].x), f2bf(ar[q].y), f2bf(ar[q].z), f2bf(ar[q].w)};
                *(ushort4*)&As[nb][r][c] = pk;
            }
#pragma unroll
            for (int q = 0; q < 3; ++q) {
                int li = q * 256 + tid, r = li >> 3, c = (li & 7) * 4;
                ushort4 pk = {f2bf(br[q].x), f2bf(br[q].y), f2bf(br[q].z), f2bf(br[q].w)};
                *(ushort4*)&Bs[nb][r][c] = pk;
            }
        }
        __syncthreads();
    }

    // epilogue: C/D layout col=lane&15, row=(lane>>4)*4+reg  [m89-verified]
#pragma unroll
    for (int i = 0; i < 2; ++i)
#pragma unroll
        for (int j = 0; j < 3; ++j)
#pragma unroll
            for (int r = 0; r < 4; ++r)
                C[(size_t)(bm + wm + i * 16 + kg * 4 + r) * NPROXY + (bn + wn + j * 16 + fr)] = acc[i][j][r];
}

// ---------------- Per-sample: CE + top-50 (histogram refinement select) + assoc ----------------
__global__ __launch_bounds__(256) void per_sample(const float* __restrict__ sims,
                                                  const int* __restrict__ cams,
                                                  const int* __restrict__ labels,
                                                  float* __restrict__ ce_out,
                                                  float* __restrict__ assoc_out)
{
    __shared__ float row[NPROXY];       // 48000 B
    __shared__ float red[256];
    __shared__ unsigned hist[256];
    __shared__ float pos_sh[N_CAMS];
    __shared__ float s_lo, s_hi;
    __shared__ int s_need;

    const int i   = blockIdx.x;
    const int tid = threadIdx.x;
    const float* s = sims + (size_t)i * NPROXY;
    const int cc  = cams[i];
    const int lab = labels[i];

    // stage row in LDS (vectorized)
    for (int p = tid; p < NPROXY / 4; p += 256)
        *(float4*)&row[p * 4] = *(const float4*)&s[p * 4];
    __syncthreads();

    // ---- CE over own-camera block ----
    const int base = cc * CLS;
    float lmax = -1e30f;
    for (int c = tid; c < CLS; c += 256) lmax = fmaxf(lmax, row[base + c]);
    red[tid] = lmax; __syncthreads();
    for (int st = 128; st > 0; st >>= 1) {
        if (tid < st) red[tid] = fmaxf(red[tid], red[tid + st]);
        __syncthreads();
    }
    const float smax = red[0];
    __syncthreads();
    float lsum = 0.f;
    for (int c = tid; c < CLS; c += 256) lsum += expf((row[base + c] - smax) * BETA_INV);
    red[tid] = lsum; __syncthreads();
    for (int st = 128; st > 0; st >>= 1) {
        if (tid < st) red[tid] += red[tid + st];
        __syncthreads();
    }
    if (tid == 0) ce_out[i] = logf(red[0]) + (smax - row[base + lab]) * BETA_INV;
    __syncthreads();

    // ---- capture positives, then mask them ----
    if (tid < N_CAMS) pos_sh[tid] = row[tid * CLS + lab];
    __syncthreads();
    if (tid < N_CAMS) row[tid * CLS + lab] = MASK_VAL;
    __syncthreads();

    // ---- masked row max M1 ----
    float mm = -1e30f;
    for (int p = tid; p < NPROXY; p += 256) mm = fmaxf(mm, row[p]);
    red[tid] = mm; __syncthreads();
    for (int st = 128; st > 0; st >>= 1) {
        if (tid < st) red[tid] = fmaxf(red[tid], red[tid + st]);
        __syncthreads();
    }
    const float M1 = red[0];
    __syncthreads();

    // ---- find 50th-largest via 4-pass histogram refinement on (lo, hi] ----
    float lo = M1 - 2.0f;            // cosine sims bounded in [-1,1]; masked -1e4 excluded
    float hi = M1 + 1e-6f;
    int need = BG_KNN;
    for (int pass = 0; pass < 4; ++pass) {
        hist[tid] = 0u;
        __syncthreads();
        const float scale = 256.0f / (hi - lo);
        for (int p = tid; p < NPROXY; p += 256) {
            float v = row[p];
            if (v > lo && v <= hi) {
                int b = (int)((v - lo) * scale);
                b = b < 0 ? 0 : (b > 255 ? 255 : b);
                atomicAdd(&hist[b], 1u);
            }
        }
        __syncthreads();
        if (tid == 0) {
            unsigned cum = 0; int sel = -1; unsigned above = 0;
            for (int b = 255; b >= 0; --b) {
                cum += hist[b];
                if (cum >= (unsigned)need) { sel = b; above = cum - hist[b]; break; }
            }
            if (sel < 0) { sel = 0; above = 0; }   // rounding-leak fallback
            s_lo = lo + (float)sel / scale;
            s_hi = lo + (float)(sel + 1) / scale;
            s_need = need - (int)above;
        }
        __syncthreads();
        lo = s_lo; hi = s_hi; need = s_need;
        __syncthreads();
    }

    // ---- final: sum exp over top-50 (strictly > hi, plus `need` ties in (lo,hi]) ----
    float pmax = -1e30f, psum = 0.f;
#pragma unroll
    for (int j = 0; j < N_CAMS; ++j) {
        pmax = fmaxf(pmax, pos_sh[j]);
        psum += pos_sh[j];
    }
    const float M = fmaxf(M1, pmax);

    float ssum = 0.f, vtie = -1e30f;
    for (int p = tid; p < NPROXY; p += 256) {
        float v = row[p];
        if (v > hi)      ssum += expf((v - M) * BETA_INV);
        else if (v > lo) vtie = fmaxf(vtie, v);
    }
    red[tid] = ssum; __syncthreads();
    for (int st = 128; st > 0; st >>= 1) {
        if (tid < st) red[tid] += red[tid + st];
        __syncthreads();
    }
    const float ssum_t = red[0];
    __syncthreads();
    red[tid] = vtie; __syncthreads();
    for (int st = 128; st > 0; st >>= 1) {
        if (tid < st) red[tid] = fmaxf(red[tid], red[tid + st]);
        __syncthreads();
    }
    if (tid == 0) {
        float vt = red[0];
        if (vt < -1e29f) vt = hi;      // fallback if ties leaked
        float total = ssum_t + (float)need * expf((vt - M) * BETA_INV);
#pragma unroll
        for (int j = 0; j < N_CAMS; ++j) total += expf((pos_sh[j] - M) * BETA_INV);
        float lse = M * BETA_INV + logf(total);
        assoc_out[i] = lse - psum * BETA_INV / (float)N_CAMS;
    }
}

// ---------------- Finalize: per-camera segment means -> scalar loss ----------------
__global__ __launch_bounds__(64) void finalize(const int* __restrict__ cams,
                                               const float* __restrict__ ce,
                                               const float* __restrict__ assoc,
                                               float* __restrict__ out)
{
    __shared__ float ce_s[N_CAMS], as_s[N_CAMS];
    __shared__ int   cnt[N_CAMS];
    int tid = threadIdx.x;
    if (tid < N_CAMS) {
        float cs = 0.f, as = 0.f; int n = 0;
        for (int i = 0; i < BATCH; ++i) {
            if (cams[i] == tid) { cs += ce[i]; as += assoc[i]; ++n; }
        }
        ce_s[tid] = cs; as_s[tid] = as; cnt[tid] = n;
    }
    __syncthreads();
    if (tid == 0) {
        float loss = 0.f;
        for (int c = 0; c < N_CAMS; ++c) {
            if (cnt[c] > 0) {
                float inv = 1.f / (float)cnt[c];
                loss += ce_s[c] * inv + 0.5f * as_s[c] * inv;
            }
        }
        out[0] = loss;
    }
}

extern "C" void kernel_launch(void* const* d_in, const int* in_sizes, int n_in,
                              void* d_out, int out_size, void* d_ws, size_t ws_size,
                              hipStream_t stream) {
    const float* feats  = (const float*)d_in[0];   // [256][2048]
    const float* mem    = (const float*)d_in[1];   // [6][2000][2048]
    const int*   cams   = (const int*)d_in[2];
    const int*   labels = (const int*)d_in[3];
    float* out = (float*)d_out;

    float* sims  = (float*)d_ws;                       // 256*12000 fp32 = 49.15 MB
    float* ce    = sims + (size_t)BATCH * NPROXY;
    float* assoc = ce + BATCH;

    gemm_mfma<<<dim3(4 * (NPROXY / GBN)), 256, 0, stream>>>(feats, mem, sims);   // 500 blocks
    per_sample<<<BATCH, 256, 0, stream>>>(sims, cams, labels, ce, assoc);
    finalize<<<1, 64, 0, stream>>>(cams, ce, assoc, out);
}

// Round 3
// 117.675 us; speedup vs baseline: 3.3941x; 1.2846x over previous
//
#include <hip/hip_runtime.h>
#include <hip/hip_bf16.h>
#include <math.h>

#define BETA_INV 20.0f          // 1/0.05
#define BG_KNN   50
#define N_CAMS   6
#define CLS      2000
#define DIM      2048
#define BATCH    256
#define NPROXY   (N_CAMS * CLS)     // 12000
#define MASK_VAL -10000.0f

typedef __attribute__((ext_vector_type(8))) short short8;
typedef __attribute__((ext_vector_type(4))) float f32x4;

__device__ __forceinline__ unsigned short f2bf(float f) {
    unsigned u = __builtin_bit_cast(unsigned, f);
    unsigned r = 0x7FFFu + ((u >> 16) & 1u);
    return (unsigned short)((u + r) >> 16);
}

// ---------------- bf16 MFMA GEMM: sims[256][12000] = feats @ mem^T ----------------
// BM=256 (full batch: each B panel read from HBM exactly once), BN=48, BK=32.
// 512 threads = 8 waves, wave tile 32x48 (2x3 frags of 16x16).
#define GBN 48
#define GBK 32
#define LDP 40   // padded LDS row (bf16): 80B stride -> only 2-way bank aliasing (free)

__global__ __launch_bounds__(512) void gemm_mfma(const float* __restrict__ A,   // [256][2048]
                                                 const float* __restrict__ Bm,  // [12000][2048]
                                                 float* __restrict__ C)         // [256][12000]
{
    __shared__ unsigned short As[2][BATCH][LDP];   // 40 KB
    __shared__ unsigned short Bs[2][GBN][LDP];     // 7.5 KB

    const int tid  = threadIdx.x;
    const int bn   = blockIdx.x * GBN;
    const int lane = tid & 63;
    const int wid  = tid >> 6;
    const int wm   = wid * 32;
    const int fr   = lane & 15;
    const int kg   = lane >> 4;              // 0..3

    const int arow = tid >> 3;               // 0..63  (A: row arow + 64*q)
    const int acol = (tid & 7) * 4;
    const bool hasB = tid < 384;
    const int brow = tid >> 3;               // 0..47 for tid<384
    const int bcol = (tid & 7) * 4;

    f32x4 acc[2][3];
#pragma unroll
    for (int i = 0; i < 2; ++i)
#pragma unroll
        for (int j = 0; j < 3; ++j) acc[i][j] = (f32x4){0.f, 0.f, 0.f, 0.f};

    float4 ar[4], br;

    // prologue: stage K-tile 0
#pragma unroll
    for (int q = 0; q < 4; ++q)
        ar[q] = *(const float4*)(A + (size_t)(q * 64 + arow) * DIM + acol);
    if (hasB) br = *(const float4*)(Bm + (size_t)(bn + brow) * DIM + bcol);
#pragma unroll
    for (int q = 0; q < 4; ++q) {
        ushort4 pk = {f2bf(ar[q].x), f2bf(ar[q].y), f2bf(ar[q].z), f2bf(ar[q].w)};
        *(ushort4*)&As[0][q * 64 + arow][acol] = pk;
    }
    if (hasB) {
        ushort4 pk = {f2bf(br.x), f2bf(br.y), f2bf(br.z), f2bf(br.w)};
        *(ushort4*)&Bs[0][brow][bcol] = pk;
    }
    __syncthreads();

    const int NT = DIM / GBK;   // 64
    for (int t = 0; t < NT; ++t) {
        const int buf = t & 1;
        if (t < NT - 1) {
            const int k0 = (t + 1) * GBK;
#pragma unroll
            for (int q = 0; q < 4; ++q)
                ar[q] = *(const float4*)(A + (size_t)(q * 64 + arow) * DIM + k0 + acol);
            if (hasB) br = *(const float4*)(Bm + (size_t)(bn + brow) * DIM + k0 + bcol);
        }
        short8 af[2], bf[3];
#pragma unroll
        for (int i = 0; i < 2; ++i)
            af[i] = *(const short8*)&As[buf][wm + i * 16 + fr][kg * 8];
#pragma unroll
        for (int j = 0; j < 3; ++j)
            bf[j] = *(const short8*)&Bs[buf][j * 16 + fr][kg * 8];
#pragma unroll
        for (int i = 0; i < 2; ++i)
#pragma unroll
            for (int j = 0; j < 3; ++j)
                acc[i][j] = __builtin_amdgcn_mfma_f32_16x16x32_bf16(af[i], bf[j], acc[i][j], 0, 0, 0);
        if (t < NT - 1) {
            const int nb = buf ^ 1;
#pragma unroll
            for (int q = 0; q < 4; ++q) {
                ushort4 pk = {f2bf(ar[q].x), f2bf(ar[q].y), f2bf(ar[q].z), f2bf(ar[q].w)};
                *(ushort4*)&As[nb][q * 64 + arow][acol] = pk;
            }
            if (hasB) {
                ushort4 pk = {f2bf(br.x), f2bf(br.y), f2bf(br.z), f2bf(br.w)};
                *(ushort4*)&Bs[nb][brow][bcol] = pk;
            }
        }
        __syncthreads();
    }

    // epilogue: C/D layout col=lane&15, row=(lane>>4)*4+reg
#pragma unroll
    for (int i = 0; i < 2; ++i)
#pragma unroll
        for (int j = 0; j < 3; ++j)
#pragma unroll
            for (int r = 0; r < 4; ++r)
                C[(size_t)(wm + i * 16 + kg * 4 + r) * NPROXY + (bn + j * 16 + fr)] = acc[i][j][r];
}

// ---------------- per-sample, register-resident (512 thr, 6x float4 each) ----------------
__device__ __forceinline__ float block_sum_f(float x, volatile float* red8, int lane, int wid) {
#pragma unroll
    for (int off = 32; off; off >>= 1) x += __shfl_xor(x, off);
    if (lane == 0) red8[wid] = x;
    __syncthreads();
    float t = 0.f;
#pragma unroll
    for (int w = 0; w < 8; ++w) t += red8[w];
    __syncthreads();
    return t;
}
__device__ __forceinline__ float block_max_f(float x, volatile float* red8, int lane, int wid) {
#pragma unroll
    for (int off = 32; off; off >>= 1) x = fmaxf(x, __shfl_xor(x, off));
    if (lane == 0) red8[wid] = x;
    __syncthreads();
    float t = -1e30f;
#pragma unroll
    for (int w = 0; w < 8; ++w) t = fmaxf(t, red8[w]);
    __syncthreads();
    return t;
}
__device__ __forceinline__ int block_sum_i(int x, volatile int* red8, int lane, int wid) {
#pragma unroll
    for (int off = 32; off; off >>= 1) x += __shfl_xor(x, off);
    if (lane == 0) red8[wid] = x;
    __syncthreads();
    int t = 0;
#pragma unroll
    for (int w = 0; w < 8; ++w) t += red8[w];
    __syncthreads();
    return t;
}

__global__ __launch_bounds__(512) void per_sample(const float* __restrict__ sims,
                                                  const int* __restrict__ cams,
                                                  const int* __restrict__ labels,
                                                  float* __restrict__ ce_out,
                                                  float* __restrict__ assoc_out)
{
    __shared__ float redf[8];
    __shared__ int   redi[8];
    __shared__ float pos_sh[N_CAMS];
    __shared__ float sh_vlab;

    const int i    = blockIdx.x;
    const int tid  = threadIdx.x;
    const int lane = tid & 63;
    const int wid  = tid >> 6;
    const float* s = sims + (size_t)i * NPROXY;
    const int cc   = cams[i];
    const int lab  = labels[i];

    // load 24 values per thread: v[ii] covers p = 4*(tid+512*ii) + c
    float4 v[6];
#pragma unroll
    for (int ii = 0; ii < 6; ++ii) {
        int q = tid + 512 * ii;
        if (q < NPROXY / 4) v[ii] = *(const float4*)(s + 4 * q);
        else v[ii] = make_float4(-1e30f, -1e30f, -1e30f, -1e30f);
    }

    // capture label value (before masking; CE uses unmasked sims)
    const int plab = cc * CLS + lab;
    const int qlab = plab >> 2, clab = plab & 3;
#pragma unroll
    for (int ii = 0; ii < 6; ++ii) {
        if ((qlab >> 9) == ii && (qlab & 511) == tid) {
            float t = (clab == 0) ? v[ii].x : (clab == 1) ? v[ii].y : (clab == 2) ? v[ii].z : v[ii].w;
            sh_vlab = t;
        }
    }

    // ---- CE over own-camera block [cc*2000, cc*2000+2000) == q in [cc*500, cc*500+500) ----
    const int qlo = cc * 500, qhi = qlo + 500;
    float m = -1e30f;
#pragma unroll
    for (int ii = 0; ii < 6; ++ii) {
        int q = tid + 512 * ii;
        if (q >= qlo && q < qhi) {
            m = fmaxf(m, fmaxf(fmaxf(v[ii].x, v[ii].y), fmaxf(v[ii].z, v[ii].w)));
        }
    }
    const float smax = block_max_f(m, redf, lane, wid);
    float ls = 0.f;
#pragma unroll
    for (int ii = 0; ii < 6; ++ii) {
        int q = tid + 512 * ii;
        if (q >= qlo && q < qhi) {
            ls += __expf((v[ii].x - smax) * BETA_INV);
            ls += __expf((v[ii].y - smax) * BETA_INV);
            ls += __expf((v[ii].z - smax) * BETA_INV);
            ls += __expf((v[ii].w - smax) * BETA_INV);
        }
    }
    const float lsum = block_sum_f(ls, redf, lane, wid);
    if (tid == 0) ce_out[i] = logf(lsum) + (smax - sh_vlab) * BETA_INV;

    // ---- capture positives (rows j*2000+lab) and mask them in-register ----
#define DOPC(II, COMP, CIDX) { \
        int p = 4 * (tid + 512 * (II)) + (CIDX); \
        int r = p - lab; \
        if (r >= 0 && r <= (N_CAMS - 1) * CLS && (r % CLS) == 0) { \
            pos_sh[r / CLS] = v[II].COMP; \
            v[II].COMP = MASK_VAL; \
        } }
#pragma unroll
    for (int ii = 0; ii < 6; ++ii) {
        DOPC(ii, x, 0); DOPC(ii, y, 1); DOPC(ii, z, 2); DOPC(ii, w, 3);
    }
#undef DOPC
    __syncthreads();   // pos_sh visible

    // ---- masked row max M1 ----
    float mm = -1e30f;
#pragma unroll
    for (int ii = 0; ii < 6; ++ii)
        mm = fmaxf(mm, fmaxf(fmaxf(v[ii].x, v[ii].y), fmaxf(v[ii].z, v[ii].w)));
    const float M1 = block_max_f(mm, redf, lane, wid);

    float pmax = -1e30f, psum = 0.f;
#pragma unroll
    for (int j = 0; j < N_CAMS; ++j) {
        float pv = pos_sh[j];
        pmax = fmaxf(pmax, pv);
        psum += pv;
    }

    // ---- 25-step bisection for the 50th-largest threshold ----
    float lo = -1.1f, hi = M1 + 1e-3f;
    int cnt_hi = 0;
    for (int it = 0; it < 25; ++it) {
        const float mid = 0.5f * (lo + hi);
        int c = 0;
#pragma unroll
        for (int ii = 0; ii < 6; ++ii) {
            c += (v[ii].x >= mid); c += (v[ii].y >= mid);
            c += (v[ii].z >= mid); c += (v[ii].w >= mid);
        }
        const int tot = block_sum_i(c, redi, lane, wid);
        if (tot >= BG_KNN) lo = mid; else { hi = mid; cnt_hi = tot; }
    }

    // ---- final: sum exp over the top-50 ----
    const float M = fmaxf(M1, pmax);
    float ss = 0.f, vt = -1e30f;
#pragma unroll
    for (int ii = 0; ii < 6; ++ii) {
#define DOF(COMP) { float x = v[ii].COMP; \
        if (x >= hi) ss += __expf((x - M) * BETA_INV); \
        else if (x >= lo) vt = fmaxf(vt, x); }
        DOF(x) DOF(y) DOF(z) DOF(w)
#undef DOF
    }
    const float ssum = block_sum_f(ss, redf, lane, wid);
    const float vtie = block_max_f(vt, redf, lane, wid);

    if (tid == 0) {
        int need = BG_KNN - cnt_hi;
        float vts = (vtie < -1e29f) ? lo : vtie;
        float total = ssum + (float)need * __expf((vts - M) * BETA_INV);
#pragma unroll
        for (int j = 0; j < N_CAMS; ++j) total += __expf((pos_sh[j] - M) * BETA_INV);
        assoc_out[i] = M * BETA_INV + logf(total) - psum * BETA_INV / (float)N_CAMS;
    }
}

// ---------------- Finalize: per-camera segment means -> scalar loss ----------------
__global__ __launch_bounds__(64) void finalize(const int* __restrict__ cams,
                                               const float* __restrict__ ce,
                                               const float* __restrict__ assoc,
                                               float* __restrict__ out)
{
    __shared__ float ce_s[N_CAMS], as_s[N_CAMS];
    __shared__ int   cnt[N_CAMS];
    int tid = threadIdx.x;
    if (tid < N_CAMS) {
        float cs = 0.f, as = 0.f; int n = 0;
        for (int i = 0; i < BATCH; ++i) {
            if (cams[i] == tid) { cs += ce[i]; as += assoc[i]; ++n; }
        }
        ce_s[tid] = cs; as_s[tid] = as; cnt[tid] = n;
    }
    __syncthreads();
    if (tid == 0) {
        float loss = 0.f;
        for (int c = 0; c < N_CAMS; ++c) {
            if (cnt[c] > 0) {
                float inv = 1.f / (float)cnt[c];
                loss += ce_s[c] * inv + 0.5f * as_s[c] * inv;
            }
        }
        out[0] = loss;
    }
}

extern "C" void kernel_launch(void* const* d_in, const int* in_sizes, int n_in,
                              void* d_out, int out_size, void* d_ws, size_t ws_size,
                              hipStream_t stream) {
    const float* feats  = (const float*)d_in[0];   // [256][2048]
    const float* mem    = (const float*)d_in[1];   // [6][2000][2048]
    const int*   cams   = (const int*)d_in[2];
    const int*   labels = (const int*)d_in[3];
    float* out = (float*)d_out;

    float* sims  = (float*)d_ws;                       // 256*12000 fp32 = 49.15 MB
    float* ce    = sims + (size_t)BATCH * NPROXY;
    float* assoc = ce + BATCH;

    gemm_mfma<<<dim3(NPROXY / GBN), 512, 0, stream>>>(feats, mem, sims);   // 250 blocks
    per_sample<<<BATCH, 512, 0, stream>>>(sims, cams, labels, ce, assoc);
    finalize<<<1, 64, 0, stream>>>(cams, ce, assoc, out);
}

// Round 4
// 100.975 us; speedup vs baseline: 3.9554x; 1.1654x over previous
//
#include <hip/hip_runtime.h>
#include <hip/hip_bf16.h>
#include <math.h>

#define BETA_INV 20.0f          // 1/0.05
#define BG_KNN   50
#define N_CAMS   6
#define CLS      2000
#define DIM      2048
#define BATCH    256
#define NPROXY   (N_CAMS * CLS)     // 12000
#define MASK_VAL -10000.0f

typedef __attribute__((ext_vector_type(8))) short short8;
typedef __attribute__((ext_vector_type(4))) float f32x4;

__device__ __forceinline__ uint2 cvt4(float4 v) {
    uint2 r;
    asm("v_cvt_pk_bf16_f32 %0, %1, %2" : "=v"(r.x) : "v"(v.x), "v"(v.y));
    asm("v_cvt_pk_bf16_f32 %0, %1, %2" : "=v"(r.y) : "v"(v.z), "v"(v.w));
    return r;
}

// ---------------- convert feats -> bf16 (once; 65536 threads x 8 elems) ----------------
__global__ __launch_bounds__(256) void conv_a(const float* __restrict__ A,
                                              unsigned short* __restrict__ Ab)
{
    const int idx = blockIdx.x * 256 + threadIdx.x;       // 0..65535
    const float4* p = (const float4*)A + (size_t)idx * 2;
    float4 v0 = p[0], v1 = p[1];
    uint2 a = cvt4(v0), b = cvt4(v1);
    *(uint4*)(Ab + (size_t)idx * 8) = make_uint4(a.x, a.y, b.x, b.y);
}

// ---------------- GEMM: sims[256][12000] = feats_bf16 @ mem^T (mem fp32, cvt inline) ----
// BM=64, BN=96, BK=64; 256 thr = 4 waves (2x2), wave 32x48 (2x3 frags 16x16x32).
// A-frags direct global->reg (L2-resident, prefetched); B staged fp32->cvt->LDS (dbuf).
#define GBM 64
#define GBN 96
#define GBK 64
#define BSTR 72                 // Bs row stride (bf16 elems) = 144 B -> conflict-free b128
#define NTT (DIM / GBK)         // 32

__global__ __launch_bounds__(256) void gemm_mfma(const unsigned short* __restrict__ Ab, // [256][2048]
                                                 const float* __restrict__ Bm,          // [12000][2048]
                                                 float* __restrict__ C)                 // [256][12000]
{
    __shared__ unsigned short Bs[2][GBN][BSTR];   // 27.6 KB

    const int tid = threadIdx.x;
    // bijective XCD chunk swizzle (nwg=500, 8 XCDs, q=62 r=4): 4 M-sharers -> same XCD
    {
    }
    const int bid = blockIdx.x;
    const int xcd = bid & 7, pos = bid >> 3;
    const int lid = (xcd < 4 ? xcd * 63 : 252 + (xcd - 4) * 62) + pos;
    const int bm = (lid & 3) * GBM;
    const int bn = (lid >> 2) * GBN;

    const int lane = tid & 63, wid = tid >> 6;
    const int wm = (wid >> 1) * 32;
    const int wn = (wid & 1) * 48;
    const int fr = lane & 15, kg = lane >> 4;

    // A fragment pointers: pa[i][ks] + t*64 is the short8 for K-tile t
    const unsigned short* pa[2][2];
#pragma unroll
    for (int i = 0; i < 2; ++i)
#pragma unroll
        for (int ks = 0; ks < 2; ++ks)
            pa[i][ks] = Ab + (size_t)(bm + wm + i * 16 + fr) * DIM + ks * 32 + kg * 8;

    // B staging: thread covers rows srow+16s (s=0..5), cols scol..scol+3 (fp32)
    const int srow = tid >> 4;
    const int scol = (tid & 15) * 4;
    const float* pb = Bm + (size_t)(bn + srow) * DIM + scol;

    f32x4 acc[2][3];
#pragma unroll
    for (int i = 0; i < 2; ++i)
#pragma unroll
        for (int j = 0; j < 3; ++j) acc[i][j] = (f32x4){0.f, 0.f, 0.f, 0.f};

    float4 br[6];
    short8 af_x[2][2], af_y[2][2];

    // prologue: stage tile 0 into Bs[0]; load af for tile 0
#pragma unroll
    for (int s = 0; s < 6; ++s)
        br[s] = *(const float4*)(pb + (size_t)s * 16 * DIM);
#pragma unroll
    for (int i = 0; i < 2; ++i)
#pragma unroll
        for (int ks = 0; ks < 2; ++ks)
            af_x[i][ks] = *(const short8*)(pa[i][ks]);
#pragma unroll
    for (int s = 0; s < 6; ++s)
        *(uint2*)&Bs[0][srow + 16 * s][scol] = cvt4(br[s]);
    __syncthreads();

#define BODY(CUR, NXT, AFC, AFN, T) do {                                              \
    if ((T) + 1 < NTT) {                                                              \
        _Pragma("unroll")                                                             \
        for (int s = 0; s < 6; ++s)                                                   \
            br[s] = *(const float4*)(pb + (size_t)s * 16 * DIM + ((T) + 1) * 64);     \
        _Pragma("unroll")                                                             \
        for (int i = 0; i < 2; ++i)                                                   \
            _Pragma("unroll")                                                         \
            for (int ks = 0; ks < 2; ++ks)                                            \
                AFN[i][ks] = *(const short8*)(pa[i][ks] + ((T) + 1) * 64);            \
    }                                                                                 \
    _Pragma("unroll")                                                                 \
    for (int ks = 0; ks < 2; ++ks)                                                    \
        _Pragma("unroll")                                                             \
        for (int j = 0; j < 3; ++j) {                                                 \
            short8 bf = *(const short8*)&Bs[CUR][wn + j * 16 + fr][ks * 32 + kg * 8]; \
            _Pragma("unroll")                                                         \
            for (int i = 0; i < 2; ++i)                                               \
                acc[i][j] = __builtin_amdgcn_mfma_f32_16x16x32_bf16(AFC[i][ks], bf, acc[i][j], 0, 0, 0); \
        }                                                                             \
    if ((T) + 1 < NTT) {                                                              \
        _Pragma("unroll")                                                             \
        for (int s = 0; s < 6; ++s)                                                   \
            *(uint2*)&Bs[NXT][srow + 16 * s][scol] = cvt4(br[s]);                     \
    }                                                                                 \
    __syncthreads();                                                                  \
} while (0)

    for (int tt = 0; tt < NTT; tt += 2) {
        BODY(0, 1, af_x, af_y, tt);
        BODY(1, 0, af_y, af_x, tt + 1);
    }
#undef BODY

    // epilogue: C/D layout col=lane&15, row=(lane>>4)*4+reg
#pragma unroll
    for (int i = 0; i < 2; ++i)
#pragma unroll
        for (int j = 0; j < 3; ++j)
#pragma unroll
            for (int r = 0; r < 4; ++r)
                C[(size_t)(bm + wm + i * 16 + kg * 4 + r) * NPROXY + (bn + wn + j * 16 + fr)] = acc[i][j][r];
}

// ---------------- per-sample, register-resident (512 thr, 6x float4 each) ----------------
__device__ __forceinline__ float block_sum_f(float x, volatile float* red8, int lane, int wid) {
#pragma unroll
    for (int off = 32; off; off >>= 1) x += __shfl_xor(x, off);
    if (lane == 0) red8[wid] = x;
    __syncthreads();
    float t = 0.f;
#pragma unroll
    for (int w = 0; w < 8; ++w) t += red8[w];
    __syncthreads();
    return t;
}
__device__ __forceinline__ float block_max_f(float x, volatile float* red8, int lane, int wid) {
#pragma unroll
    for (int off = 32; off; off >>= 1) x = fmaxf(x, __shfl_xor(x, off));
    if (lane == 0) red8[wid] = x;
    __syncthreads();
    float t = -1e30f;
#pragma unroll
    for (int w = 0; w < 8; ++w) t = fmaxf(t, red8[w]);
    __syncthreads();
    return t;
}
__device__ __forceinline__ int block_sum_i(int x, volatile int* red8, int lane, int wid) {
#pragma unroll
    for (int off = 32; off; off >>= 1) x += __shfl_xor(x, off);
    if (lane == 0) red8[wid] = x;
    __syncthreads();
    int t = 0;
#pragma unroll
    for (int w = 0; w < 8; ++w) t += red8[w];
    __syncthreads();
    return t;
}

__global__ __launch_bounds__(512) void per_sample(const float* __restrict__ sims,
                                                  const int* __restrict__ cams,
                                                  const int* __restrict__ labels,
                                                  float* __restrict__ ce_out,
                                                  float* __restrict__ assoc_out)
{
    __shared__ float redf[8];
    __shared__ int   redi[8];
    __shared__ float pos_sh[N_CAMS];
    __shared__ float sh_vlab;

    const int i    = blockIdx.x;
    const int tid  = threadIdx.x;
    const int lane = tid & 63;
    const int wid  = tid >> 6;
    const float* s = sims + (size_t)i * NPROXY;
    const int cc   = cams[i];
    const int lab  = labels[i];

    float4 v[6];
#pragma unroll
    for (int ii = 0; ii < 6; ++ii) {
        int q = tid + 512 * ii;
        if (q < NPROXY / 4) v[ii] = *(const float4*)(s + 4 * q);
        else v[ii] = make_float4(-1e30f, -1e30f, -1e30f, -1e30f);
    }

    const int plab = cc * CLS + lab;
    const int qlab = plab >> 2, clab = plab & 3;
#pragma unroll
    for (int ii = 0; ii < 6; ++ii) {
        if ((qlab >> 9) == ii && (qlab & 511) == tid) {
            float t = (clab == 0) ? v[ii].x : (clab == 1) ? v[ii].y : (clab == 2) ? v[ii].z : v[ii].w;
            sh_vlab = t;
        }
    }

    // ---- CE over own-camera block: q in [cc*500, cc*500+500) ----
    const int qlo = cc * 500, qhi = qlo + 500;
    float m = -1e30f;
#pragma unroll
    for (int ii = 0; ii < 6; ++ii) {
        int q = tid + 512 * ii;
        if (q >= qlo && q < qhi)
            m = fmaxf(m, fmaxf(fmaxf(v[ii].x, v[ii].y), fmaxf(v[ii].z, v[ii].w)));
    }
    const float smax = block_max_f(m, redf, lane, wid);
    float ls = 0.f;
#pragma unroll
    for (int ii = 0; ii < 6; ++ii) {
        int q = tid + 512 * ii;
        if (q >= qlo && q < qhi) {
            ls += __expf((v[ii].x - smax) * BETA_INV);
            ls += __expf((v[ii].y - smax) * BETA_INV);
            ls += __expf((v[ii].z - smax) * BETA_INV);
            ls += __expf((v[ii].w - smax) * BETA_INV);
        }
    }
    const float lsum = block_sum_f(ls, redf, lane, wid);
    if (tid == 0) ce_out[i] = logf(lsum) + (smax - sh_vlab) * BETA_INV;

    // ---- capture positives (rows j*2000+lab), mask in-register ----
#define DOPC(II, COMP, CIDX) { \
        int p = 4 * (tid + 512 * (II)) + (CIDX); \
        int r = p - lab; \
        if (r >= 0 && r <= (N_CAMS - 1) * CLS && (r % CLS) == 0) { \
            pos_sh[r / CLS] = v[II].COMP; \
            v[II].COMP = MASK_VAL; \
        } }
#pragma unroll
    for (int ii = 0; ii < 6; ++ii) {
        DOPC(ii, x, 0); DOPC(ii, y, 1); DOPC(ii, z, 2); DOPC(ii, w, 3);
    }
#undef DOPC
    __syncthreads();

    // ---- masked row max M1 ----
    float mm = -1e30f;
#pragma unroll
    for (int ii = 0; ii < 6; ++ii)
        mm = fmaxf(mm, fmaxf(fmaxf(v[ii].x, v[ii].y), fmaxf(v[ii].z, v[ii].w)));
    const float M1 = block_max_f(mm, redf, lane, wid);

    float pmax = -1e30f, psum = 0.f;
#pragma unroll
    for (int j = 0; j < N_CAMS; ++j) {
        float pv = pos_sh[j];
        pmax = fmaxf(pmax, pv);
        psum += pv;
    }

    // ---- 20-step bisection for 50th-largest (exact via tie handling) ----
    float lo = M1 - 0.5f, hi = M1 + 1e-4f;
    int cnt_hi = 0;
    for (int it = 0; it < 20; ++it) {
        const float mid = 0.5f * (lo + hi);
        int c = 0;
#pragma unroll
        for (int ii = 0; ii < 6; ++ii) {
            c += (v[ii].x >= mid); c += (v[ii].y >= mid);
            c += (v[ii].z >= mid); c += (v[ii].w >= mid);
        }
        const int tot = block_sum_i(c, redi, lane, wid);
        if (tot >= BG_KNN) lo = mid; else { hi = mid; cnt_hi = tot; }
    }

    // ---- final: sum exp over the top-50 ----
    const float M = fmaxf(M1, pmax);
    float ss = 0.f, vt = -1e30f;
#pragma unroll
    for (int ii = 0; ii < 6; ++ii) {
#define DOF(COMP) { float x = v[ii].COMP; \
        if (x >= hi) ss += __expf((x - M) * BETA_INV); \
        else if (x >= lo) vt = fmaxf(vt, x); }
        DOF(x) DOF(y) DOF(z) DOF(w)
#undef DOF
    }
    const float ssum = block_sum_f(ss, redf, lane, wid);
    const float vtie = block_max_f(vt, redf, lane, wid);

    if (tid == 0) {
        int need = BG_KNN - cnt_hi;
        float vts = (vtie < -1e29f) ? lo : vtie;
        float total = ssum + (float)need * __expf((vts - M) * BETA_INV);
#pragma unroll
        for (int j = 0; j < N_CAMS; ++j) total += __expf((pos_sh[j] - M) * BETA_INV);
        assoc_out[i] = M * BETA_INV + logf(total) - psum * BETA_INV / (float)N_CAMS;
    }
}

// ---------------- Finalize ----------------
__global__ __launch_bounds__(64) void finalize(const int* __restrict__ cams,
                                               const float* __restrict__ ce,
                                               const float* __restrict__ assoc,
                                               float* __restrict__ out)
{
    __shared__ float ce_s[N_CAMS], as_s[N_CAMS];
    __shared__ int   cnt[N_CAMS];
    int tid = threadIdx.x;
    if (tid < N_CAMS) {
        float cs = 0.f, as = 0.f; int n = 0;
        for (int i = 0; i < BATCH; ++i) {
            if (cams[i] == tid) { cs += ce[i]; as += assoc[i]; ++n; }
        }
        ce_s[tid] = cs; as_s[tid] = as; cnt[tid] = n;
    }
    __syncthreads();
    if (tid == 0) {
        float loss = 0.f;
        for (int c = 0; c < N_CAMS; ++c) {
            if (cnt[c] > 0) {
                float inv = 1.f / (float)cnt[c];
                loss += ce_s[c] * inv + 0.5f * as_s[c] * inv;
            }
        }
        out[0] = loss;
    }
}

extern "C" void kernel_launch(void* const* d_in, const int* in_sizes, int n_in,
                              void* d_out, int out_size, void* d_ws, size_t ws_size,
                              hipStream_t stream) {
    const float* feats  = (const float*)d_in[0];   // [256][2048]
    const float* mem    = (const float*)d_in[1];   // [6][2000][2048]
    const int*   cams   = (const int*)d_in[2];
    const int*   labels = (const int*)d_in[3];
    float* out = (float*)d_out;

    float* sims  = (float*)d_ws;                        // 12.29 MB
    float* ce    = sims + (size_t)BATCH * NPROXY;
    float* assoc = ce + BATCH;
    unsigned short* A_bf = (unsigned short*)(assoc + BATCH);   // 1 MB, 16B-aligned

    conv_a<<<256, 256, 0, stream>>>(feats, A_bf);
    gemm_mfma<<<500, 256, 0, stream>>>(A_bf, mem, sims);
    per_sample<<<BATCH, 512, 0, stream>>>(sims, cams, labels, ce, assoc);
    finalize<<<1, 64, 0, stream>>>(cams, ce, assoc, out);
}

// Round 5
// 97.287 us; speedup vs baseline: 4.1054x; 1.0379x over previous
//
#include <hip/hip_runtime.h>
#include <hip/hip_bf16.h>
#include <math.h>

#define BETA_INV 20.0f          // 1/0.05
#define BG_KNN   50
#define N_CAMS   6
#define CLS      2000
#define DIM      2048
#define BATCH    256
#define NPROXY   (N_CAMS * CLS)     // 12000
#define MASK_VAL -10000.0f

typedef __attribute__((ext_vector_type(8))) short short8;
typedef __attribute__((ext_vector_type(4))) float f32x4;

__device__ __forceinline__ uint2 cvt4(float4 v) {
    uint2 r;
    asm("v_cvt_pk_bf16_f32 %0, %1, %2" : "=v"(r.x) : "v"(v.x), "v"(v.y));
    asm("v_cvt_pk_bf16_f32 %0, %1, %2" : "=v"(r.y) : "v"(v.z), "v"(v.w));
    return r;
}

// ---------------- convert feats -> bf16 (once; 65536 threads x 8 elems) ----------------
__global__ __launch_bounds__(256) void conv_a(const float* __restrict__ A,
                                              unsigned short* __restrict__ Ab)
{
    const int idx = blockIdx.x * 256 + threadIdx.x;       // 0..65535
    const float4* p = (const float4*)A + (size_t)idx * 2;
    float4 v0 = p[0], v1 = p[1];
    uint2 a = cvt4(v0), b = cvt4(v1);
    *(uint4*)(Ab + (size_t)idx * 8) = make_uint4(a.x, a.y, b.x, b.y);
}

// ---------------- GEMM: sims[256][12000] = feats_bf16 @ mem^T (mem fp32, cvt inline) ----
// BM=64, BN=96, BK=64; 512 thr = 8 waves, wave tile 16x48 (1x3 frags of 16x16x32).
// 2-stage register pipeline: B(t+2)/A(t+1) loads issue at step t; LDS double-buffered.
#define GBM 64
#define GBN 96
#define GBK 64
#define BSTR 72                 // Bs row stride (bf16) = 144 B -> only 2-way aliasing (free)
#define NTT (DIM / GBK)         // 32

__global__ __launch_bounds__(512) void gemm_mfma(const unsigned short* __restrict__ Ab, // [256][2048] bf16
                                                 const float* __restrict__ Bm,          // [12000][2048] f32
                                                 float* __restrict__ C)                 // [256][12000]
{
    __shared__ unsigned short Bs[2][GBN][BSTR];   // 27.6 KB

    const int tid = threadIdx.x;
    // bijective XCD chunk swizzle (nwg=500, 8 XCDs, q=62 r=4): 4 M-sharers -> same XCD
    const int bid = blockIdx.x;
    const int xcd = bid & 7, pos = bid >> 3;
    const int lid = (xcd < 4 ? xcd * 63 : 252 + (xcd - 4) * 62) + pos;
    const int bm = (lid & 3) * GBM;
    const int bn = (lid >> 2) * GBN;

    const int lane = tid & 63, wid = tid >> 6;
    const int wm = (wid >> 1) * 16;          // 0,16,32,48
    const int wn = (wid & 1) * 48;
    const int fr = lane & 15, kg = lane >> 4;

    // A fragment pointers: pa[ks] + t*64 is the short8 for K-tile t
    const unsigned short* pa[2];
#pragma unroll
    for (int ks = 0; ks < 2; ++ks)
        pa[ks] = Ab + (size_t)(bm + wm + fr) * DIM + ks * 32 + kg * 8;

    // B staging: thread covers rows srow+32s (s=0..2), cols scol..scol+3 (fp32)
    const int srow = tid >> 4;               // 0..31
    const int scol = (tid & 15) * 4;
    const float* pb = Bm + (size_t)(bn + srow) * DIM + scol;

    f32x4 acc[3];
#pragma unroll
    for (int j = 0; j < 3; ++j) acc[j] = (f32x4){0.f, 0.f, 0.f, 0.f};

    float4 br_a[3], br_b[3];
    short8 af_a[2], af_b[2];

    // ---- prologue ----
#pragma unroll
    for (int s = 0; s < 3; ++s)
        br_a[s] = *(const float4*)(pb + (size_t)s * 32 * DIM);          // B(0)
#pragma unroll
    for (int ks = 0; ks < 2; ++ks)
        af_a[ks] = *(const short8*)(pa[ks]);                            // A(0)
#pragma unroll
    for (int s = 0; s < 3; ++s)
        *(uint2*)&Bs[0][srow + 32 * s][scol] = cvt4(br_a[s]);           // tile 0 -> LDS[0]
#pragma unroll
    for (int s = 0; s < 3; ++s)
        br_a[s] = *(const float4*)(pb + (size_t)s * 32 * DIM + 64);     // B(1) in flight
    __syncthreads();

#define BODY(T, CUR, NXT, BRC, BRN, AFC, AFN) do {                                    \
    if ((T) + 2 < NTT) {                                                              \
        _Pragma("unroll")                                                             \
        for (int s = 0; s < 3; ++s)                                                   \
            BRN[s] = *(const float4*)(pb + (size_t)s * 32 * DIM + ((T) + 2) * 64);    \
    }                                                                                 \
    if ((T) + 1 < NTT) {                                                              \
        _Pragma("unroll")                                                             \
        for (int ks = 0; ks < 2; ++ks)                                                \
            AFN[ks] = *(const short8*)(pa[ks] + ((T) + 1) * 64);                      \
    }                                                                                 \
    _Pragma("unroll")                                                                 \
    for (int ks = 0; ks < 2; ++ks)                                                    \
        _Pragma("unroll")                                                             \
        for (int j = 0; j < 3; ++j) {                                                 \
            short8 bf = *(const short8*)&Bs[CUR][wn + j * 16 + fr][ks * 32 + kg * 8]; \
            acc[j] = __builtin_amdgcn_mfma_f32_16x16x32_bf16(AFC[ks], bf, acc[j], 0, 0, 0); \
        }                                                                             \
    if ((T) + 1 < NTT) {                                                              \
        _Pragma("unroll")                                                             \
        for (int s = 0; s < 3; ++s)                                                   \
            *(uint2*)&Bs[NXT][srow + 32 * s][scol] = cvt4(BRC[s]);                    \
    }                                                                                 \
    __syncthreads();                                                                  \
} while (0)

    for (int t = 0; t < NTT; t += 2) {
        BODY(t,     0, 1, br_a, br_b, af_a, af_b);
        BODY(t + 1, 1, 0, br_b, br_a, af_b, af_a);
    }
#undef BODY

    // epilogue: C/D layout col=lane&15, row=(lane>>4)*4+reg
#pragma unroll
    for (int j = 0; j < 3; ++j)
#pragma unroll
        for (int r = 0; r < 4; ++r)
            C[(size_t)(bm + wm + kg * 4 + r) * NPROXY + (bn + wn + j * 16 + fr)] = acc[j][r];
}

// ---------------- per-sample, register-resident (512 thr, 6x float4 each) ----------------
__device__ __forceinline__ float block_sum_f(float x, volatile float* red8, int lane, int wid) {
#pragma unroll
    for (int off = 32; off; off >>= 1) x += __shfl_xor(x, off);
    if (lane == 0) red8[wid] = x;
    __syncthreads();
    float t = 0.f;
#pragma unroll
    for (int w = 0; w < 8; ++w) t += red8[w];
    __syncthreads();
    return t;
}
__device__ __forceinline__ float block_max_f(float x, volatile float* red8, int lane, int wid) {
#pragma unroll
    for (int off = 32; off; off >>= 1) x = fmaxf(x, __shfl_xor(x, off));
    if (lane == 0) red8[wid] = x;
    __syncthreads();
    float t = -1e30f;
#pragma unroll
    for (int w = 0; w < 8; ++w) t = fmaxf(t, red8[w]);
    __syncthreads();
    return t;
}
__device__ __forceinline__ int block_sum_i(int x, volatile int* red8, int lane, int wid) {
#pragma unroll
    for (int off = 32; off; off >>= 1) x += __shfl_xor(x, off);
    if (lane == 0) red8[wid] = x;
    __syncthreads();
    int t = 0;
#pragma unroll
    for (int w = 0; w < 8; ++w) t += red8[w];
    __syncthreads();
    return t;
}

__global__ __launch_bounds__(512) void per_sample(const float* __restrict__ sims,
                                                  const int* __restrict__ cams,
                                                  const int* __restrict__ labels,
                                                  float* __restrict__ ce_out,
                                                  float* __restrict__ assoc_out)
{
    __shared__ float redf[8];
    __shared__ int   redi[8];
    __shared__ float pos_sh[N_CAMS];
    __shared__ float sh_vlab;

    const int i    = blockIdx.x;
    const int tid  = threadIdx.x;
    const int lane = tid & 63;
    const int wid  = tid >> 6;
    const float* s = sims + (size_t)i * NPROXY;
    const int cc   = cams[i];
    const int lab  = labels[i];

    float4 v[6];
#pragma unroll
    for (int ii = 0; ii < 6; ++ii) {
        int q = tid + 512 * ii;
        if (q < NPROXY / 4) v[ii] = *(const float4*)(s + 4 * q);
        else v[ii] = make_float4(-1e30f, -1e30f, -1e30f, -1e30f);
    }

    const int plab = cc * CLS + lab;
    const int qlab = plab >> 2, clab = plab & 3;
#pragma unroll
    for (int ii = 0; ii < 6; ++ii) {
        if ((qlab >> 9) == ii && (qlab & 511) == tid) {
            float t = (clab == 0) ? v[ii].x : (clab == 1) ? v[ii].y : (clab == 2) ? v[ii].z : v[ii].w;
            sh_vlab = t;
        }
    }

    // ---- CE over own-camera block: q in [cc*500, cc*500+500) ----
    const int qlo = cc * 500, qhi = qlo + 500;
    float m = -1e30f;
#pragma unroll
    for (int ii = 0; ii < 6; ++ii) {
        int q = tid + 512 * ii;
        if (q >= qlo && q < qhi)
            m = fmaxf(m, fmaxf(fmaxf(v[ii].x, v[ii].y), fmaxf(v[ii].z, v[ii].w)));
    }
    const float smax = block_max_f(m, redf, lane, wid);
    float ls = 0.f;
#pragma unroll
    for (int ii = 0; ii < 6; ++ii) {
        int q = tid + 512 * ii;
        if (q >= qlo && q < qhi) {
            ls += __expf((v[ii].x - smax) * BETA_INV);
            ls += __expf((v[ii].y - smax) * BETA_INV);
            ls += __expf((v[ii].z - smax) * BETA_INV);
            ls += __expf((v[ii].w - smax) * BETA_INV);
        }
    }
    const float lsum = block_sum_f(ls, redf, lane, wid);
    if (tid == 0) ce_out[i] = logf(lsum) + (smax - sh_vlab) * BETA_INV;

    // ---- capture positives (rows j*2000+lab), mask in-register ----
#define DOPC(II, COMP, CIDX) { \
        int p = 4 * (tid + 512 * (II)) + (CIDX); \
        int r = p - lab; \
        if (r >= 0 && r <= (N_CAMS - 1) * CLS && (r % CLS) == 0) { \
            pos_sh[r / CLS] = v[II].COMP; \
            v[II].COMP = MASK_VAL; \
        } }
#pragma unroll
    for (int ii = 0; ii < 6; ++ii) {
        DOPC(ii, x, 0); DOPC(ii, y, 1); DOPC(ii, z, 2); DOPC(ii, w, 3);
    }
#undef DOPC
    __syncthreads();

    // ---- masked row max M1 ----
    float mm = -1e30f;
#pragma unroll
    for (int ii = 0; ii < 6; ++ii)
        mm = fmaxf(mm, fmaxf(fmaxf(v[ii].x, v[ii].y), fmaxf(v[ii].z, v[ii].w)));
    const float M1 = block_max_f(mm, redf, lane, wid);

    float pmax = -1e30f, psum = 0.f;
#pragma unroll
    for (int j = 0; j < N_CAMS; ++j) {
        float pv = pos_sh[j];
        pmax = fmaxf(pmax, pv);
        psum += pv;
    }

    // ---- 20-step bisection for 50th-largest (ties handled exactly below) ----
    float lo = M1 - 0.5f, hi = M1 + 1e-4f;
    int cnt_hi = 0;
    for (int it = 0; it < 20; ++it) {
        const float mid = 0.5f * (lo + hi);
        int c = 0;
#pragma unroll
        for (int ii = 0; ii < 6; ++ii) {
            c += (v[ii].x >= mid); c += (v[ii].y >= mid);
            c += (v[ii].z >= mid); c += (v[ii].w >= mid);
        }
        const int tot = block_sum_i(c, redi, lane, wid);
        if (tot >= BG_KNN) lo = mid; else { hi = mid; cnt_hi = tot; }
    }

    // ---- final: sum exp over the top-50 ----
    const float M = fmaxf(M1, pmax);
    float ss = 0.f, vt = -1e30f;
#pragma unroll
    for (int ii = 0; ii < 6; ++ii) {
#define DOF(COMP) { float x = v[ii].COMP; \
        if (x >= hi) ss += __expf((x - M) * BETA_INV); \
        else if (x >= lo) vt = fmaxf(vt, x); }
        DOF(x) DOF(y) DOF(z) DOF(w)
#undef DOF
    }
    const float ssum = block_sum_f(ss, redf, lane, wid);
    const float vtie = block_max_f(vt, redf, lane, wid);

    if (tid == 0) {
        int need = BG_KNN - cnt_hi;
        float vts = (vtie < -1e29f) ? lo : vtie;
        float total = ssum + (float)need * __expf((vts - M) * BETA_INV);
#pragma unroll
        for (int j = 0; j < N_CAMS; ++j) total += __expf((pos_sh[j] - M) * BETA_INV);
        assoc_out[i] = M * BETA_INV + logf(total) - psum * BETA_INV / (float)N_CAMS;
    }
}

// ---------------- Finalize ----------------
__global__ __launch_bounds__(64) void finalize(const int* __restrict__ cams,
                                               const float* __restrict__ ce,
                                               const float* __restrict__ assoc,
                                               float* __restrict__ out)
{
    __shared__ float ce_s[N_CAMS], as_s[N_CAMS];
    __shared__ int   cnt[N_CAMS];
    int tid = threadIdx.x;
    if (tid < N_CAMS) {
        float cs = 0.f, as = 0.f; int n = 0;
        for (int i = 0; i < BATCH; ++i) {
            if (cams[i] == tid) { cs += ce[i]; as += assoc[i]; ++n; }
        }
        ce_s[tid] = cs; as_s[tid] = as; cnt[tid] = n;
    }
    __syncthreads();
    if (tid == 0) {
        float loss = 0.f;
        for (int c = 0; c < N_CAMS; ++c) {
            if (cnt[c] > 0) {
                float inv = 1.f / (float)cnt[c];
                loss += ce_s[c] * inv + 0.5f * as_s[c] * inv;
            }
        }
        out[0] = loss;
    }
}

extern "C" void kernel_launch(void* const* d_in, const int* in_sizes, int n_in,
                              void* d_out, int out_size, void* d_ws, size_t ws_size,
                              hipStream_t stream) {
    const float* feats  = (const float*)d_in[0];   // [256][2048]
    const float* mem    = (const float*)d_in[1];   // [6][2000][2048]
    const int*   cams   = (const int*)d_in[2];
    const int*   labels = (const int*)d_in[3];
    float* out = (float*)d_out;

    float* sims  = (float*)d_ws;                        // 12.29 MB
    float* ce    = sims + (size_t)BATCH * NPROXY;
    float* assoc = ce + BATCH;
    unsigned short* A_bf = (unsigned short*)(assoc + BATCH);   // 1 MB, 16B-aligned

    conv_a<<<256, 256, 0, stream>>>(feats, A_bf);
    gemm_mfma<<<500, 512, 0, stream>>>(A_bf, mem, sims);
    per_sample<<<BATCH, 512, 0, stream>>>(sims, cams, labels, ce, assoc);
    finalize<<<1, 64, 0, stream>>>(cams, ce, assoc, out);
}

// Round 6
// 78.561 us; speedup vs baseline: 5.0840x; 1.2384x over previous
//
#include <hip/hip_runtime.h>
#include <hip/hip_bf16.h>
#include <math.h>

#define BETA_INV 20.0f          // 1/0.05
#define BG_KNN   50
#define N_CAMS   6
#define CLS      2000
#define DIM      2048
#define BATCH    256
#define NPROXY   (N_CAMS * CLS)     // 12000
#define MASK_VAL -10000.0f

typedef __attribute__((ext_vector_type(8))) short short8;
typedef __attribute__((ext_vector_type(4))) float f32x4;

__device__ __forceinline__ uint2 cvt4(float4 v) {
    uint2 r;
    asm("v_cvt_pk_bf16_f32 %0, %1, %2" : "=v"(r.x) : "v"(v.x), "v"(v.y));
    asm("v_cvt_pk_bf16_f32 %0, %1, %2" : "=v"(r.y) : "v"(v.z), "v"(v.w));
    return r;
}

// ---------------- convert feats -> bf16 (once; 65536 threads x 8 elems) ----------------
__global__ __launch_bounds__(256) void conv_a(const float* __restrict__ A,
                                              unsigned short* __restrict__ Ab)
{
    const int idx = blockIdx.x * 256 + threadIdx.x;       // 0..65535
    const float4* p = (const float4*)A + (size_t)idx * 2;
    float4 v0 = p[0], v1 = p[1];
    uint2 a = cvt4(v0), b = cvt4(v1);
    *(uint4*)(Ab + (size_t)idx * 8) = make_uint4(a.x, a.y, b.x, b.y);
}

// ---------------- GEMM: sims[256][12000] = feats_bf16 @ mem^T (mem fp32, cvt inline) ----
// BM=64, BN=96, BK=64; 512 thr = 8 waves, wave tile 16x48 (1x3 frags of 16x16x32).
// 2-stage register pipeline; raw s_barrier (lgkmcnt-only) keeps global loads in
// flight ACROSS barriers (no vmcnt(0) drain per step).
#define GBM 64
#define GBN 96
#define GBK 64
#define BSTR 72                 // Bs row stride (bf16) = 144 B -> only 2-way aliasing (free)
#define NTT (DIM / GBK)         // 32

__global__ __launch_bounds__(512, 2) void gemm_mfma(const unsigned short* __restrict__ Ab, // [256][2048] bf16
                                                    const float* __restrict__ Bm,          // [12000][2048] f32
                                                    float* __restrict__ C)                 // [256][12000]
{
    __shared__ unsigned short Bs[2][GBN][BSTR];   // 27.6 KB

    const int tid = threadIdx.x;
    // bijective XCD chunk swizzle (nwg=500, 8 XCDs, q=62 r=4): 4 M-sharers -> same XCD
    const int bid = blockIdx.x;
    const int xcd = bid & 7, pos = bid >> 3;
    const int lid = (xcd < 4 ? xcd * 63 : 252 + (xcd - 4) * 62) + pos;
    const int bm = (lid & 3) * GBM;
    const int bn = (lid >> 2) * GBN;

    const int lane = tid & 63, wid = tid >> 6;
    const int wm = (wid >> 1) * 16;          // 0,16,32,48
    const int wn = (wid & 1) * 48;
    const int fr = lane & 15, kg = lane >> 4;

    // A fragment pointers: pa[ks] + t*64 is the short8 for K-tile t
    const unsigned short* pa[2];
#pragma unroll
    for (int ks = 0; ks < 2; ++ks)
        pa[ks] = Ab + (size_t)(bm + wm + fr) * DIM + ks * 32 + kg * 8;

    // B staging: thread covers rows srow+32s (s=0..2), cols scol..scol+3 (fp32)
    const int srow = tid >> 4;               // 0..31
    const int scol = (tid & 15) * 4;
    const float* pb = Bm + (size_t)(bn + srow) * DIM + scol;

    f32x4 acc[3];
#pragma unroll
    for (int j = 0; j < 3; ++j) acc[j] = (f32x4){0.f, 0.f, 0.f, 0.f};

    float4 br_a[3], br_b[3];
    short8 af_a[2], af_b[2];

    // ---- prologue ----
#pragma unroll
    for (int s = 0; s < 3; ++s)
        br_a[s] = *(const float4*)(pb + (size_t)s * 32 * DIM);          // B(0)
#pragma unroll
    for (int ks = 0; ks < 2; ++ks)
        af_a[ks] = *(const short8*)(pa[ks]);                            // A(0)
#pragma unroll
    for (int s = 0; s < 3; ++s)
        *(uint2*)&Bs[0][srow + 32 * s][scol] = cvt4(br_a[s]);           // tile 0 -> LDS[0]
#pragma unroll
    for (int s = 0; s < 3; ++s)
        br_a[s] = *(const float4*)(pb + (size_t)s * 32 * DIM + 64);     // B(1) in flight
    asm volatile("s_waitcnt lgkmcnt(0)" ::: "memory");
    __builtin_amdgcn_sched_barrier(0);
    __builtin_amdgcn_s_barrier();
    __builtin_amdgcn_sched_barrier(0);

#define BODY(T, CUR, NXT, BRC, BRN, AFC, AFN) do {                                    \
    if ((T) + 2 < NTT) {                                                              \
        _Pragma("unroll")                                                             \
        for (int s = 0; s < 3; ++s)                                                   \
            BRN[s] = *(const float4*)(pb + (size_t)s * 32 * DIM + ((T) + 2) * 64);    \
    }                                                                                 \
    if ((T) + 1 < NTT) {                                                              \
        _Pragma("unroll")                                                             \
        for (int ks = 0; ks < 2; ++ks)                                                \
            AFN[ks] = *(const short8*)(pa[ks] + ((T) + 1) * 64);                      \
    }                                                                                 \
    __builtin_amdgcn_sched_barrier(0);                                                \
    _Pragma("unroll")                                                                 \
    for (int ks = 0; ks < 2; ++ks)                                                    \
        _Pragma("unroll")                                                             \
        for (int j = 0; j < 3; ++j) {                                                 \
            short8 bf = *(const short8*)&Bs[CUR][wn + j * 16 + fr][ks * 32 + kg * 8]; \
            acc[j] = __builtin_amdgcn_mfma_f32_16x16x32_bf16(AFC[ks], bf, acc[j], 0, 0, 0); \
        }                                                                             \
    if ((T) + 1 < NTT) {                                                              \
        _Pragma("unroll")                                                             \
        for (int s = 0; s < 3; ++s)                                                   \
            *(uint2*)&Bs[NXT][srow + 32 * s][scol] = cvt4(BRC[s]);                    \
    }                                                                                 \
    asm volatile("s_waitcnt lgkmcnt(0)" ::: "memory");                                \
    __builtin_amdgcn_sched_barrier(0);                                                \
    __builtin_amdgcn_s_barrier();                                                     \
    __builtin_amdgcn_sched_barrier(0);                                                \
} while (0)

    for (int t = 0; t < NTT; t += 2) {
        BODY(t,     0, 1, br_a, br_b, af_a, af_b);
        BODY(t + 1, 1, 0, br_b, br_a, af_b, af_a);
    }
#undef BODY

    // epilogue: C/D layout col=lane&15, row=(lane>>4)*4+reg
#pragma unroll
    for (int j = 0; j < 3; ++j)
#pragma unroll
        for (int r = 0; r < 4; ++r)
            C[(size_t)(bm + wm + kg * 4 + r) * NPROXY + (bn + wn + j * 16 + fr)] = acc[j][r];
}

// ---------------- per-sample, register-resident (512 thr, 6x float4 each) ----------------
__device__ __forceinline__ float block_sum_f(float x, volatile float* red8, int lane, int wid) {
#pragma unroll
    for (int off = 32; off; off >>= 1) x += __shfl_xor(x, off);
    if (lane == 0) red8[wid] = x;
    __syncthreads();
    float t = 0.f;
#pragma unroll
    for (int w = 0; w < 8; ++w) t += red8[w];
    __syncthreads();
    return t;
}
__device__ __forceinline__ float block_max_f(float x, volatile float* red8, int lane, int wid) {
#pragma unroll
    for (int off = 32; off; off >>= 1) x = fmaxf(x, __shfl_xor(x, off));
    if (lane == 0) red8[wid] = x;
    __syncthreads();
    float t = -1e30f;
#pragma unroll
    for (int w = 0; w < 8; ++w) t = fmaxf(t, red8[w]);
    __syncthreads();
    return t;
}
__device__ __forceinline__ int block_sum_i(int x, volatile int* red8, int lane, int wid) {
#pragma unroll
    for (int off = 32; off; off >>= 1) x += __shfl_xor(x, off);
    if (lane == 0) red8[wid] = x;
    __syncthreads();
    int t = 0;
#pragma unroll
    for (int w = 0; w < 8; ++w) t += red8[w];
    __syncthreads();
    return t;
}

__global__ __launch_bounds__(512) void per_sample(const float* __restrict__ sims,
                                                  const int* __restrict__ cams,
                                                  const int* __restrict__ labels,
                                                  float* __restrict__ ce_out,
                                                  float* __restrict__ assoc_out)
{
    __shared__ float redf[8];
    __shared__ int   redi[8];
    __shared__ float pos_sh[N_CAMS];
    __shared__ float sh_vlab;

    const int i    = blockIdx.x;
    const int tid  = threadIdx.x;
    const int lane = tid & 63;
    const int wid  = tid >> 6;
    const float* s = sims + (size_t)i * NPROXY;
    const int cc   = cams[i];
    const int lab  = labels[i];

    float4 v[6];
#pragma unroll
    for (int ii = 0; ii < 6; ++ii) {
        int q = tid + 512 * ii;
        if (q < NPROXY / 4) v[ii] = *(const float4*)(s + 4 * q);
        else v[ii] = make_float4(-1e30f, -1e30f, -1e30f, -1e30f);
    }

    const int plab = cc * CLS + lab;
    const int qlab = plab >> 2, clab = plab & 3;
#pragma unroll
    for (int ii = 0; ii < 6; ++ii) {
        if ((qlab >> 9) == ii && (qlab & 511) == tid) {
            float t = (clab == 0) ? v[ii].x : (clab == 1) ? v[ii].y : (clab == 2) ? v[ii].z : v[ii].w;
            sh_vlab = t;
        }
    }

    // ---- CE over own-camera block: q in [cc*500, cc*500+500) ----
    const int qlo = cc * 500, qhi = qlo + 500;
    float m = -1e30f;
#pragma unroll
    for (int ii = 0; ii < 6; ++ii) {
        int q = tid + 512 * ii;
        if (q >= qlo && q < qhi)
            m = fmaxf(m, fmaxf(fmaxf(v[ii].x, v[ii].y), fmaxf(v[ii].z, v[ii].w)));
    }
    const float smax = block_max_f(m, redf, lane, wid);
    float ls = 0.f;
#pragma unroll
    for (int ii = 0; ii < 6; ++ii) {
        int q = tid + 512 * ii;
        if (q >= qlo && q < qhi) {
            ls += __expf((v[ii].x - smax) * BETA_INV);
            ls += __expf((v[ii].y - smax) * BETA_INV);
            ls += __expf((v[ii].z - smax) * BETA_INV);
            ls += __expf((v[ii].w - smax) * BETA_INV);
        }
    }
    const float lsum = block_sum_f(ls, redf, lane, wid);
    if (tid == 0) ce_out[i] = logf(lsum) + (smax - sh_vlab) * BETA_INV;

    // ---- capture positives (rows j*2000+lab), mask in-register ----
#define DOPC(II, COMP, CIDX) { \
        int p = 4 * (tid + 512 * (II)) + (CIDX); \
        int r = p - lab; \
        if (r >= 0 && r <= (N_CAMS - 1) * CLS && (r % CLS) == 0) { \
            pos_sh[r / CLS] = v[II].COMP; \
            v[II].COMP = MASK_VAL; \
        } }
#pragma unroll
    for (int ii = 0; ii < 6; ++ii) {
        DOPC(ii, x, 0); DOPC(ii, y, 1); DOPC(ii, z, 2); DOPC(ii, w, 3);
    }
#undef DOPC
    __syncthreads();

    // ---- masked row max M1 ----
    float mm = -1e30f;
#pragma unroll
    for (int ii = 0; ii < 6; ++ii)
        mm = fmaxf(mm, fmaxf(fmaxf(v[ii].x, v[ii].y), fmaxf(v[ii].z, v[ii].w)));
    const float M1 = block_max_f(mm, redf, lane, wid);

    float pmax = -1e30f, psum = 0.f;
#pragma unroll
    for (int j = 0; j < N_CAMS; ++j) {
        float pv = pos_sh[j];
        pmax = fmaxf(pmax, pv);
        psum += pv;
    }

    // ---- 20-step bisection for 50th-largest (ties handled exactly below) ----
    float lo = M1 - 0.5f, hi = M1 + 1e-4f;
    int cnt_hi = 0;
    for (int it = 0; it < 20; ++it) {
        const float mid = 0.5f * (lo + hi);
        int c = 0;
#pragma unroll
        for (int ii = 0; ii < 6; ++ii) {
            c += (v[ii].x >= mid); c += (v[ii].y >= mid);
            c += (v[ii].z >= mid); c += (v[ii].w >= mid);
        }
        const int tot = block_sum_i(c, redi, lane, wid);
        if (tot >= BG_KNN) lo = mid; else { hi = mid; cnt_hi = tot; }
    }

    // ---- final: sum exp over the top-50 ----
    const float M = fmaxf(M1, pmax);
    float ss = 0.f, vt = -1e30f;
#pragma unroll
    for (int ii = 0; ii < 6; ++ii) {
#define DOF(COMP) { float x = v[ii].COMP; \
        if (x >= hi) ss += __expf((x - M) * BETA_INV); \
        else if (x >= lo) vt = fmaxf(vt, x); }
        DOF(x) DOF(y) DOF(z) DOF(w)
#undef DOF
    }
    const float ssum = block_sum_f(ss, redf, lane, wid);
    const float vtie = block_max_f(vt, redf, lane, wid);

    if (tid == 0) {
        int need = BG_KNN - cnt_hi;
        float vts = (vtie < -1e29f) ? lo : vtie;
        float total = ssum + (float)need * __expf((vts - M) * BETA_INV);
#pragma unroll
        for (int j = 0; j < N_CAMS; ++j) total += __expf((pos_sh[j] - M) * BETA_INV);
        assoc_out[i] = M * BETA_INV + logf(total) - psum * BETA_INV / (float)N_CAMS;
    }
}

// ---------------- Finalize: parallel per-camera segment means -> scalar loss ----------------
__global__ __launch_bounds__(256) void finalize(const int* __restrict__ cams,
                                                const float* __restrict__ ce,
                                                const float* __restrict__ assoc,
                                                float* __restrict__ out)
{
    __shared__ float ce_s[N_CAMS], as_s[N_CAMS];
    __shared__ int   cnt[N_CAMS];
    const int tid = threadIdx.x;
    if (tid < N_CAMS) { ce_s[tid] = 0.f; as_s[tid] = 0.f; cnt[tid] = 0; }
    __syncthreads();
    const int c = cams[tid];
    atomicAdd(&ce_s[c], ce[tid]);
    atomicAdd(&as_s[c], assoc[tid]);
    atomicAdd(&cnt[c], 1);
    __syncthreads();
    if (tid == 0) {
        float loss = 0.f;
        for (int k = 0; k < N_CAMS; ++k) {
            if (cnt[k] > 0) {
                float inv = 1.f / (float)cnt[k];
                loss += ce_s[k] * inv + 0.5f * as_s[k] * inv;
            }
        }
        out[0] = loss;
    }
}

extern "C" void kernel_launch(void* const* d_in, const int* in_sizes, int n_in,
                              void* d_out, int out_size, void* d_ws, size_t ws_size,
                              hipStream_t stream) {
    const float* feats  = (const float*)d_in[0];   // [256][2048]
    const float* mem    = (const float*)d_in[1];   // [6][2000][2048]
    const int*   cams   = (const int*)d_in[2];
    const int*   labels = (const int*)d_in[3];
    float* out = (float*)d_out;

    float* sims  = (float*)d_ws;                        // 12.29 MB
    float* ce    = sims + (size_t)BATCH * NPROXY;
    float* assoc = ce + BATCH;
    unsigned short* A_bf = (unsigned short*)(assoc + BATCH);   // 1 MB, 16B-aligned

    conv_a<<<256, 256, 0, stream>>>(feats, A_bf);
    gemm_mfma<<<500, 512, 0, stream>>>(A_bf, mem, sims);
    per_sample<<<BATCH, 512, 0, stream>>>(sims, cams, labels, ce, assoc);
    finalize<<<1, 256, 0, stream>>>(cams, ce, assoc, out);
}